// Round 10
// baseline (1129.838 us; speedup 1.0000x reference)
//
#include <hip/hip_runtime.h>
#include <cstdint>
#include <cstddef>

#define BB 128
#define TT 512
#define DD 100
#define HH 100
#define NG 400   // 4*H
#define LL 25
#define TS 32    // scan tile (steps per burst)
#define NTILE 16
#define F_LOG2E 1.44269504088896340736f
#define F_LN2   0.69314718055994530942f

typedef __decltype(__builtin_amdgcn_cvt_pkrtz(0.f, 0.f)) h2_t;
typedef _Float16 v8h __attribute__((ext_vector_type(8)));
typedef float v4f __attribute__((ext_vector_type(4)));

__device__ __forceinline__ h2_t bc_h2(unsigned int u) {
  return __builtin_bit_cast(h2_t, u);
}
__device__ __forceinline__ unsigned int pk(float x, float y) {
  return __builtin_bit_cast(unsigned int, __builtin_amdgcn_cvt_pkrtz(x, y));
}
// round-to-nearest-even fp16 pack (matches scalar (__fp16) h-store numerics)
__device__ __forceinline__ unsigned int pk_rte(float x, float y) {
  unsigned short a = __builtin_bit_cast(unsigned short, (__fp16)x);
  unsigned short c = __builtin_bit_cast(unsigned short, (__fp16)y);
  return (unsigned int)a | ((unsigned int)c << 16);
}

__device__ __forceinline__ float fdot2(h2_t a, h2_t b, float c) {
#if __has_builtin(__builtin_amdgcn_fdot2)
  return __builtin_amdgcn_fdot2(a, b, c, false);
#else
  return c + (float)a[0] * (float)b[0] + (float)a[1] * (float)b[1];
#endif
}

__device__ __forceinline__ float fexp2(float x) { return __builtin_amdgcn_exp2f(x); }
__device__ __forceinline__ float flog2(float x) { return __builtin_amdgcn_logf(x); }
__device__ __forceinline__ float frcp(float x)  { return __builtin_amdgcn_rcpf(x); }

__device__ __forceinline__ float sigmoid_f(float x) {
  return frcp(1.f + fexp2(-F_LOG2E * x));
}
__device__ __forceinline__ float tanh_f(float x) {
  float e = fexp2(2.f * F_LOG2E * x);
  return 1.f - 2.f * frcp(e + 1.f);
}

template <int CTRL>
__device__ __forceinline__ float qadd(float v) {
#if __has_builtin(__builtin_amdgcn_mov_dpp)
  int m = __builtin_amdgcn_mov_dpp(__builtin_bit_cast(int, v), CTRL, 0xF, 0xF, true);
  return v + __builtin_bit_cast(float, m);
#else
  int x = (CTRL == 177) ? 1 : 2;
  return v + __shfl_xor(v, x);
#endif
}

template <int LANE>
__device__ __forceinline__ float qbcast(float v) {
#if __has_builtin(__builtin_amdgcn_mov_dpp)
  int m = __builtin_amdgcn_mov_dpp(__builtin_bit_cast(int, v), LANE * 0x55, 0xF, 0xF, true);
  return __builtin_bit_cast(float, m);
#else
  return __shfl(v, (threadIdx.x & 63 & ~3) + LANE);
#endif
}

__device__ __forceinline__ float rfl(float v) {
  return __builtin_bit_cast(float,
      __builtin_amdgcn_readfirstlane(__builtin_bit_cast(int, v)));
}

__device__ __forceinline__ void wave_fence() {
#if __has_builtin(__builtin_amdgcn_wave_barrier)
  __builtin_amdgcn_wave_barrier();
#endif
}

// LDS-visibility-only barrier (vmcnt left free): imm 0xC07F.
__device__ __forceinline__ void lds_barrier() {
  __builtin_amdgcn_s_waitcnt(0xC07F);
  __builtin_amdgcn_s_barrier();
}

// ---------------------------------------------------------------------------
// FUSED BiLSTM + x-GEMM + emissions (v10 = 4x2 fuse, third cap attempt).
// One block per batch b, 1024 thr / 16 waves: half = tid>>9 is the dir.
// Each half runs v4's verified program verbatim on its own LDS buffers.
// Mechanism under test: each SIMD hosts TWO INDEPENDENT scan chains
// (fwd + bwd) -> one chain's stalls are filled by the other's issue.
// CAP HISTORY: (1024,4) -> VGPR 64, spill (r8). (1024,2) -> VGPR 64, spill
// (r9): hipcc treats the 2nd arg as a min-occupancy constraint, forcing
// >=32 waves/CU -> cap 64. FIX: __launch_bounds__(1024) alone — the
// compiler must only make the 16-wave block schedulable (16 waves/CU =
// 4/SIMD -> cap 512/4 = 128), which is this code's natural allocation.
// Expected tell: VGPR_Count=128, FETCH ~25 MB.
// ---------------------------------------------------------------------------
__global__ __launch_bounds__(1024) void lstm_fused4x2(
    const int* __restrict__ tok, const float* __restrict__ emb,
    const float* __restrict__ w_ih_f, const float* __restrict__ w_ih_b,
    const float* __restrict__ b_ih_f, const float* __restrict__ b_hh_f,
    const float* __restrict__ b_ih_b, const float* __restrict__ b_hh_b,
    const float* __restrict__ w_hh_f, const float* __restrict__ w_hh_b,
    const float* __restrict__ w_tag, const float* __restrict__ b_tag,
    float* __restrict__ em_f, float* __restrict__ em_b,
    float* __restrict__ out_zero)
{
  const int tid_g = threadIdx.x;
  const int half  = tid_g >> 9;     // 0 = fwd, 1 = bwd
  const int tid   = tid_g & 511;    // half-local thread id (v4's tid)
  const int b     = blockIdx.x;
  const int dir   = half;
  if (blockIdx.x == 0 && tid_g == 0) *out_zero = 0.f;
  const float* w_hh = dir ? w_hh_b : w_hh_f;
  const float* w_ih = dir ? w_ih_b : w_ih_f;
  const float* b_ih = dir ? b_ih_b : b_ih_f;
  const float* b_hh = dir ? b_hh_b : b_hh_f;
  float* emo = dir ? em_b : em_f;

  __shared__ __align__(16) unsigned short gin_all[2 * TS * 400];   // 51.2 KB
  __shared__ __align__(16) unsigned int   xlds_all[2 * TS * 68];   // 17.4 KB
  __shared__ __align__(16) unsigned int   hhist_all[2 * TS * 68];  // 17.4 KB
  __shared__ __align__(16) unsigned int   hls_all[2][2][56];       // 0.9 KB

  unsigned short* gin_lds = gin_all  + half * (TS * 400);
  unsigned int*   xlds    = xlds_all + half * (TS * 68);
  unsigned int*   hhist   = hhist_all + half * (TS * 68);
  unsigned int*   hls0    = hls_all[half][0];
  unsigned int*   hls1    = hls_all[half][1];

  // burst lane mapping (within half)
  const int wv   = tid >> 6;
  const int lane = tid & 63;
  const int l16  = lane & 15;
  const int quad = lane >> 4;
  const int c0b  = (25 * wv) >> 3;
  const int c1b  = (25 * (wv + 1)) >> 3;
  const int ncol = c1b - c0b;   // 3 or 4

  // ---- one-time: B fragments from global w_ih into registers ----
  v8h bfr[4][4];
  int pcol[4];
#pragma unroll
  for (int ci = 0; ci < 4; ++ci) {
    const int cc = (ci < ncol) ? (c0b + ci) : c0b;
    const int n  = 16 * cc + l16;
    const float* wr = w_ih + (size_t)n * DD;
#pragma unroll
    for (int f = 0; f < 3; ++f) {
      const float* wp = wr + f * 32 + quad * 8;
      float4 va = *(const float4*)(wp);
      float4 vb = *(const float4*)(wp + 4);
      uint4 u;
      u.x = pk(va.x, va.y); u.y = pk(va.z, va.w);
      u.z = pk(vb.x, vb.y); u.w = pk(vb.z, vb.w);
      bfr[ci][f] = __builtin_bit_cast(v8h, u);
    }
    {
      uint4 u = {0u, 0u, 0u, 0u};
      if (quad == 0) {
        float4 va = *(const float4*)(wr + 96);
        u.x = pk(va.x, va.y); u.y = pk(va.z, va.w);
      }
      bfr[ci][3] = __builtin_bit_cast(v8h, u);
    }
    const int qn = (n * 41) >> 12;            // n/100 for n<400
    pcol[ci] = ((n - 100 * qn) << 2) + qn;    // store permutation
  }

  // ---- xlds / hhist K-pad zero (per half) ----
  for (int i = tid; i < TS * 18; i += 512) {
    int row = i / 18;
    int d = i - row * 18;
    xlds[row * 68 + 50 + d] = 0u;
    hhist[row * 68 + 50 + d] = 0u;
  }

  // ---- scan state: waves 0-3 of each half, lane = 2*j + s2 ----
  const bool uact = tid < 200;
  const int j  = tid >> 1;
  const int s2 = tid & 1;

  h2_t wG0[25], wG1[25], wG2[25], wG3[25];
  float bias0 = 0.f, bias1 = 0.f, bias2 = 0.f, bias3 = 0.f;
  if (uact) {
    const float* r0 = w_hh + (size_t)(0 * 100 + j) * HH + 50 * s2;
    const float* r1 = w_hh + (size_t)(1 * 100 + j) * HH + 50 * s2;
    const float* r2 = w_hh + (size_t)(2 * 100 + j) * HH + 50 * s2;
    const float* r3 = w_hh + (size_t)(3 * 100 + j) * HH + 50 * s2;
#pragma unroll
    for (int d = 0; d < 25; ++d) {
      float2 v0 = *(const float2*)(r0 + 2 * d);
      float2 v1 = *(const float2*)(r1 + 2 * d);
      float2 v2 = *(const float2*)(r2 + 2 * d);
      float2 v3 = *(const float2*)(r3 + 2 * d);
      wG0[d] = __builtin_amdgcn_cvt_pkrtz(v0.x, v0.y);
      wG1[d] = __builtin_amdgcn_cvt_pkrtz(v1.x, v1.y);
      wG2[d] = __builtin_amdgcn_cvt_pkrtz(v2.x, v2.y);
      wG3[d] = __builtin_amdgcn_cvt_pkrtz(v3.x, v3.y);
    }
    bias0 = b_ih[j]       + b_hh[j];
    bias1 = b_ih[100 + j] + b_hh[100 + j];
    bias2 = b_ih[200 + j] + b_hh[200 + j];
    bias3 = b_ih[300 + j] + b_hh[300 + j];
  }

  // ---- emission GEMM state: waves 4-7 of each half ----
  const int ew    = wv - 4;
  const int ecb   = ew & 1;          // label col-block (0: l 0-15, 1: l 16-24)
  const int erg   = (ew >> 1) & 1;   // step row-group (0: 0-15, 1: 16-31)
  const int encol = 16 * ecb + l16;  // output label index
  const bool eact2 = (wv >= 4) && (encol < LL);
  v8h etag[4];
  float ebias = 0.f;
  if (wv >= 4) {
#pragma unroll
    for (int f = 0; f < 3; ++f) {
      uint4 u = {0u, 0u, 0u, 0u};
      if (eact2) {
        const float* wp = w_tag + (size_t)encol * 200 + dir * 100 + f * 32 + quad * 8;
        float4 va = *(const float4*)(wp);
        float4 vb = *(const float4*)(wp + 4);
        u.x = pk(va.x, va.y); u.y = pk(va.z, va.w);
        u.z = pk(vb.x, vb.y); u.w = pk(vb.z, vb.w);
      }
      etag[f] = __builtin_bit_cast(v8h, u);
    }
    {
      uint4 u = {0u, 0u, 0u, 0u};
      if (eact2 && quad == 0) {
        float4 va = *(const float4*)(w_tag + (size_t)encol * 200 + dir * 100 + 96);
        u.x = pk(va.x, va.y); u.y = pk(va.z, va.w);
      }
      etag[3] = __builtin_bit_cast(v8h, u);
    }
    if (eact2 && dir == 0) ebias = b_tag[encol];
  }

  if (tid < 56) { hls0[tid] = 0u; hls1[tid] = 0u; }

  // x staging mapping: thread t<416 covers (row = t/13, seg = t%13)
  const int tprow = tid / 13;
  const int tps   = tid - 13 * tprow;
  const bool tp_act = tid < 416;

  // initial x prefetch (tile 0)
  float4 xa = {0, 0, 0, 0}, xb = {0, 0, 0, 0};
  if (tp_act) {
    int ii = tprow;
    int tt = dir ? (TT - 1 - ii) : ii;
    int tk = tok[b * TT + tt];
    const float* xp = emb + (size_t)tk * DD + 8 * tps;
    xa = *(const float4*)xp;
    if (tps < 12) xb = *(const float4*)(xp + 4);
  }

  float c = 0.f;
  uint2 gnext = {0u, 0u};

#define SD2(d, hw) { h2_t hv = bc_h2(hw);                                  \
  p0 = fdot2(wG0[d], hv, p0); p1 = fdot2(wG1[d], hv, p1);                  \
  p2 = fdot2(wG2[d], hv, p2); p3 = fdot2(wG3[d], hv, p3); }

#define SCAN2(HRD, HWR, ROW)                                               \
  {                                                                        \
    if (uact) {                                                            \
      uint2 gcurr = gnext;                                                 \
      int nr = ((ROW) < TS - 1) ? (ROW) + 1 : TS - 1;                      \
      gnext = ((const uint2*)(gin_lds + nr * 400))[j];                     \
      const unsigned int* hp = (HRD) + 28 * s2;                            \
      uint4 u0 = *((const uint4*)hp);                                      \
      uint4 u1 = *((const uint4*)(hp + 4));                                \
      uint4 u2 = *((const uint4*)(hp + 8));                                \
      uint4 u3 = *((const uint4*)(hp + 12));                               \
      uint4 u4 = *((const uint4*)(hp + 16));                               \
      uint4 u5 = *((const uint4*)(hp + 20));                               \
      unsigned int u6 = hp[24];                                            \
      float p0 = 0.f, p1 = 0.f, p2 = 0.f, p3 = 0.f;                        \
      SD2(0, u0.x)  SD2(1, u0.y)  SD2(2, u0.z)  SD2(3, u0.w)               \
      SD2(4, u1.x)  SD2(5, u1.y)  SD2(6, u1.z)  SD2(7, u1.w)               \
      SD2(8, u2.x)  SD2(9, u2.y)  SD2(10, u2.z) SD2(11, u2.w)              \
      SD2(12, u3.x) SD2(13, u3.y) SD2(14, u3.z) SD2(15, u3.w)              \
      SD2(16, u4.x) SD2(17, u4.y) SD2(18, u4.z) SD2(19, u4.w)              \
      SD2(20, u5.x) SD2(21, u5.y) SD2(22, u5.z) SD2(23, u5.w)              \
      SD2(24, u6)                                                          \
      p0 = qadd<177>(p0); p1 = qadd<177>(p1);                              \
      p2 = qadd<177>(p2); p3 = qadd<177>(p3);                              \
      h2_t glo = bc_h2(gcurr.x), ghi = bc_h2(gcurr.y);                     \
      float gi = p0 + bias0 + (float)glo[0];                               \
      float gf = p1 + bias1 + (float)glo[1];                               \
      float gg = p2 + bias2 + (float)ghi[0];                               \
      float go = p3 + bias3 + (float)ghi[1];                               \
      float iv = sigmoid_f(gi);                                            \
      float fv = sigmoid_f(gf);                                            \
      float gv = tanh_f(gg);                                               \
      float ov = sigmoid_f(go);                                            \
      c = fmaf(fv, c, iv * gv);                                            \
      float hvv = ov * tanh_f(c);                                          \
      float hnb = qbcast<2>(hvv);                                          \
      if ((tid & 3) == 0) {                                                \
        int k = tid >> 2;                                                  \
        unsigned int val = pk_rte(hvv, hnb);                               \
        (HWR)[k + (k >= 25 ? 3 : 0)] = val;                                \
        hhist[(ROW) * 68 + k] = val;                                       \
      }                                                                    \
    }                                                                      \
    lds_barrier();                                                         \
  }

#define EMIT_GEMM(TB)                                                      \
  {                                                                        \
    const unsigned int* hb = hhist + (erg * 16 + l16) * 68 + quad * 4;     \
    v8h ah0 = __builtin_bit_cast(v8h, *(const uint4*)(hb));                \
    v8h ah1 = __builtin_bit_cast(v8h, *(const uint4*)(hb + 16));           \
    v8h ah2 = __builtin_bit_cast(v8h, *(const uint4*)(hb + 32));           \
    v8h ah3 = __builtin_bit_cast(v8h, *(const uint4*)(hb + 48));           \
    v4f ea = {0.f, 0.f, 0.f, 0.f};                                         \
    ea = __builtin_amdgcn_mfma_f32_16x16x32_f16(ah0, etag[0], ea, 0, 0, 0);\
    ea = __builtin_amdgcn_mfma_f32_16x16x32_f16(ah1, etag[1], ea, 0, 0, 0);\
    ea = __builtin_amdgcn_mfma_f32_16x16x32_f16(ah2, etag[2], ea, 0, 0, 0);\
    ea = __builtin_amdgcn_mfma_f32_16x16x32_f16(ah3, etag[3], ea, 0, 0, 0);\
    if (eact2) {                                                           \
      const int tb = (TB) + erg * 16 + quad * 4;                           \
      _Pragma("unroll")                                                    \
      for (int r = 0; r < 4; ++r) {                                        \
        int t = dir ? (TT - 1 - (tb + r)) : (tb + r);                      \
        emo[((size_t)b * TT + t) * LL + encol] = ea[r] + ebias;            \
      }                                                                    \
    }                                                                      \
  }

  __syncthreads();  // pads / hls init complete

  for (int T = 0; T < NTILE; ++T) {
    // ---- write prefetched x regs to xlds ----
    if (tp_act) {
      unsigned int* xr = xlds + tprow * 68 + 4 * tps;
      if (tps < 12) {
        uint4 u;
        u.x = pk(xa.x, xa.y); u.y = pk(xa.z, xa.w);
        u.z = pk(xb.x, xb.y); u.w = pk(xb.z, xb.w);
        *(uint4*)xr = u;
      } else {
        xr[0] = pk(xa.x, xa.y);
        xr[1] = pk(xa.z, xa.w);
      }
    }
    __syncthreads();

    // ---- BURST ----
    {
      v8h af[2][4];
#pragma unroll
      for (int rg = 0; rg < 2; ++rg)
#pragma unroll
        for (int f = 0; f < 4; ++f)
          af[rg][f] = __builtin_bit_cast(v8h,
              *(const uint4*)(xlds + (rg * 16 + l16) * 68 + f * 16 + quad * 4));

      // kick off next tile's x prefetch (stays in flight through the scan)
      if (tp_act && T + 1 < NTILE) {
        int ii = (T + 1) * TS + tprow;
        int tt = dir ? (TT - 1 - ii) : ii;
        int tk = tok[b * TT + tt];
        const float* xp = emb + (size_t)tk * DD + 8 * tps;
        xa = *(const float4*)xp;
        if (tps < 12) xb = *(const float4*)(xp + 4);
      }

      __fp16* gout = (__fp16*)gin_lds;
#pragma unroll
      for (int ci = 0; ci < 4; ++ci) {
        if (ci >= ncol) break;
        const int p = pcol[ci];
#pragma unroll
        for (int rg = 0; rg < 2; ++rg) {
          v4f acc = {0.f, 0.f, 0.f, 0.f};
          acc = __builtin_amdgcn_mfma_f32_16x16x32_f16(af[rg][0], bfr[ci][0], acc, 0, 0, 0);
          acc = __builtin_amdgcn_mfma_f32_16x16x32_f16(af[rg][1], bfr[ci][1], acc, 0, 0, 0);
          acc = __builtin_amdgcn_mfma_f32_16x16x32_f16(af[rg][2], bfr[ci][2], acc, 0, 0, 0);
          acc = __builtin_amdgcn_mfma_f32_16x16x32_f16(af[rg][3], bfr[ci][3], acc, 0, 0, 0);
          const int rowb = rg * 16 + quad * 4;
#pragma unroll
          for (int r = 0; r < 4; ++r)
            gout[(rowb + r) * 400 + p] = (__fp16)acc[r];
        }
      }

      // ---- emission GEMM for previous tile's h (waves 4-7 of each half) ----
      if (wv >= 4 && T > 0) {
        EMIT_GEMM((T - 1) * TS)
      }
    }
    __syncthreads();
    if (uact) gnext = ((const uint2*)gin_lds)[j];

    // ---- TS scan steps ----
    for (int it = 0; it < TS; it += 2) {
      SCAN2(hls0, hls1, it)
      SCAN2(hls1, hls0, it + 1)
    }
  }

  // epilogue: emissions for the final tile (hhist holds tile NTILE-1's h;
  // last scan step ended with lds_barrier, so it is visible)
  if (wv >= 4) {
    EMIT_GEMM((NTILE - 1) * TS)
  }
#undef EMIT_GEMM
#undef SCAN2
#undef SD2
}

// ===========================================================================
// CRF — parallel chunked scan (round-1 versions, verified).
// ===========================================================================
#define CHN  8
#define CLEN 64
__device__ __align__(16) float g_PT[(size_t)BB * CHN * LL * 28];  // 2.87 MB

__global__ __launch_bounds__(128, 2) void crf_chunks(
    const float* __restrict__ em_f, const float* __restrict__ em_b,
    const float* __restrict__ trans)
{
  const int tid = threadIdx.x;
  const int b   = blockIdx.x >> 3;
  const int c   = blockIdx.x & 7;
  const int ts  = c * CLEN;

  __shared__ __align__(16) float Al[2][LL][28];   // double-buffered A
  __shared__ __align__(16) float el[CLEN][32];    // e_t[j] = exp(em_t[j])

  // ---- stage e rows (2 threads per time step) ----
  {
    const int row  = tid >> 1;        // 0..63
    const int half = tid & 1;
    const int jb   = half ? 13 : 0;
    const int nj   = half ? 12 : 13;
    const float* pf = em_f + ((size_t)b * TT + ts + row) * LL;
    const float* pb = em_b + ((size_t)b * TT + ts + row) * LL;
    for (int q = 0; q < nj; ++q) {
      int jj = jb + q;
      el[row][jj] = fexp2((pf[jj] + pb[jj]) * F_LOG2E);
    }
  }

  const bool lact = tid < 125;
  const int i  = tid / 5;          // output row 0..24
  const int jg = tid - 5 * i;      // col group 0..4
  const int j0 = 5 * jg;

  // ---- E' = exp(T)*2^-5, columns j0..j0+4, in registers (125 VGPR) ----
  float E[25][5];
  if (lact) {
#pragma unroll
    for (int k = 0; k < 25; ++k) {
      const float* tr = trans + k * 25 + j0;
#pragma unroll
      for (int u = 0; u < 5; ++u)
        E[k][u] = fexp2(tr[u] * F_LOG2E - 5.f);
    }
    // A = I
#pragma unroll
    for (int u = 0; u < 5; ++u)
      Al[0][i][j0 + u] = (i == j0 + u) ? 1.f : 0.f;
  }
  __syncthreads();

  int p = 0;
  const int s0 = (c == 0) ? 1 : 0;   // chunk 0 covers t = 1..63
  for (int st = s0; st < CLEN; ++st) {
    if (lact) {
      const float* ar = &Al[p][i][0];
      float4 q0 = *(const float4*)(ar);
      float4 q1 = *(const float4*)(ar + 4);
      float4 q2 = *(const float4*)(ar + 8);
      float4 q3 = *(const float4*)(ar + 12);
      float4 q4 = *(const float4*)(ar + 16);
      float4 q5 = *(const float4*)(ar + 20);
      float a24 = ar[24];
      float e0 = el[st][j0];
      float e1 = el[st][j0 + 1];
      float e2 = el[st][j0 + 2];
      float e3 = el[st][j0 + 3];
      float e4 = el[st][j0 + 4];
      float av[25] = {q0.x, q0.y, q0.z, q0.w, q1.x, q1.y, q1.z, q1.w,
                      q2.x, q2.y, q2.z, q2.w, q3.x, q3.y, q3.z, q3.w,
                      q4.x, q4.y, q4.z, q4.w, q5.x, q5.y, q5.z, q5.w, a24};
      float c0 = 0.f, c1 = 0.f, c2 = 0.f, c3 = 0.f, c4 = 0.f;
#pragma unroll
      for (int k = 0; k < 25; ++k) {
        float avk = av[k];
        c0 = fmaf(avk, E[k][0], c0);
        c1 = fmaf(avk, E[k][1], c1);
        c2 = fmaf(avk, E[k][2], c2);
        c3 = fmaf(avk, E[k][3], c3);
        c4 = fmaf(avk, E[k][4], c4);
      }
      float* wr = &Al[p ^ 1][i][j0];
      wr[0] = c0 * e0; wr[1] = c1 * e1; wr[2] = c2 * e2;
      wr[3] = c3 * e3; wr[4] = c4 * e4;
    }
    __syncthreads();
    p ^= 1;
  }

  // ---- store P transposed: g_PT[(b*8+c)*25 + j][i], row stride 28 ----
  if (lact) {
    const size_t base = ((size_t)(b * CHN + c)) * LL;
#pragma unroll
    for (int u = 0; u < 5; ++u)
      g_PT[(base + (j0 + u)) * 28 + i] = Al[p][i][j0 + u];
  }
}

__global__ __launch_bounds__(128) void crf_combine(
    const float* __restrict__ em_f, const float* __restrict__ em_b,
    const int* __restrict__ tags, const int* __restrict__ lengths,
    const float* __restrict__ trans,
    const float* __restrict__ startt, const float* __restrict__ endt,
    float* __restrict__ out)
{
  const int tid = threadIdx.x;
  const int b   = blockIdx.x;

  __shared__ __align__(16) float Vs[28];

  if (tid < 64) {
    // -------- wave 0: logZ via chunk-matrix chain --------
    const int lane = tid;
    const int j = (lane < LL) ? lane : 0;
    const float* ef0 = em_f + (size_t)b * TT * LL;
    const float* eb0 = em_b + (size_t)b * TT * LL;
    float v = fexp2((startt[j] + ef0[j] + eb0[j]) * F_LOG2E);  // alpha0
    float C = 0.f;  // accumulated log2 scale
    for (int c = 0; c < CHN; ++c) {
      if (lane < LL) Vs[lane] = v;
      wave_fence();
      float4 s0 = *(const float4*)(Vs);
      float4 s1 = *(const float4*)(Vs + 4);
      float4 s2 = *(const float4*)(Vs + 8);
      float4 s3 = *(const float4*)(Vs + 12);
      float4 s4 = *(const float4*)(Vs + 16);
      float4 s5 = *(const float4*)(Vs + 20);
      float s24 = Vs[24];
      wave_fence();
      const float* pr = g_PT + ((size_t)(b * CHN + c) * LL + j) * 28;
      float4 p0 = *(const float4*)(pr);
      float4 p1 = *(const float4*)(pr + 4);
      float4 p2 = *(const float4*)(pr + 8);
      float4 p3 = *(const float4*)(pr + 12);
      float4 p4 = *(const float4*)(pr + 16);
      float4 p5 = *(const float4*)(pr + 20);
      float p24 = pr[24];
      float nv = s0.x * p0.x;
      nv = fmaf(s0.y, p0.y, nv); nv = fmaf(s0.z, p0.z, nv); nv = fmaf(s0.w, p0.w, nv);
      nv = fmaf(s1.x, p1.x, nv); nv = fmaf(s1.y, p1.y, nv);
      nv = fmaf(s1.z, p1.z, nv); nv = fmaf(s1.w, p1.w, nv);
      nv = fmaf(s2.x, p2.x, nv); nv = fmaf(s2.y, p2.y, nv);
      nv = fmaf(s2.z, p2.z, nv); nv = fmaf(s2.w, p2.w, nv);
      nv = fmaf(s3.x, p3.x, nv); nv = fmaf(s3.y, p3.y, nv);
      nv = fmaf(s3.z, p3.z, nv); nv = fmaf(s3.w, p3.w, nv);
      nv = fmaf(s4.x, p4.x, nv); nv = fmaf(s4.y, p4.y, nv);
      nv = fmaf(s4.z, p4.z, nv); nv = fmaf(s4.w, p4.w, nv);
      nv = fmaf(s5.x, p5.x, nv); nv = fmaf(s5.y, p5.y, nv);
      nv = fmaf(s5.z, p5.z, nv); nv = fmaf(s5.w, p5.w, nv);
      nv = fmaf(s24, p24, nv);
      // renormalize by lane-0 exponent (all entries same magnitude class)
      float nv0 = rfl(nv);
      int k = ((__builtin_bit_cast(int, nv0) >> 23) & 255) - 127;
      k = (k > 100) ? 100 : ((k < -100) ? -100 : k);
      float scl = __builtin_bit_cast(float, (127 - k) << 23);
      v = nv * scl;
      C += (float)k;
    }
    float term = (lane < LL) ? v * fexp2(endt[j] * F_LOG2E) : 0.f;
    for (int o = 32; o > 0; o >>= 1) term += __shfl_down(term, o);
    if (lane == 0)
      atomicAdd(out, (flog2(term) + C + 5.f * 511.f) * F_LN2);
  } else {
    // -------- wave 1: gold path score --------
    const int lane = tid & 63;
    const int len = lengths[b];
    float acc = 0.f;
#pragma unroll
    for (int k = 0; k < 8; ++k) {
      int t = k * 64 + lane;
      int tg = tags[b * TT + t];
      size_t ei = ((size_t)b * TT + t) * LL + tg;
      float e = em_f[ei] + em_b[ei];
      float term;
      if (t == 0) term = startt[tg] + e;
      else        term = trans[tags[b * TT + t - 1] * LL + tg] + e;
      if (t == len - 1) term += endt[tg];
      if (t < len) acc += term;
    }
    for (int o = 32; o > 0; o >>= 1) acc += __shfl_down(acc, o);
    if (lane == 0) atomicAdd(out, -acc);
  }
}

extern "C" void kernel_launch(void* const* d_in, const int* in_sizes, int n_in,
                              void* d_out, int out_size, void* d_ws, size_t ws_size,
                              hipStream_t stream) {
  const int*   tok   = (const int*)d_in[0];
  const int*   tags  = (const int*)d_in[1];
  const int*   lens  = (const int*)d_in[2];
  const float* emb   = (const float*)d_in[3];
  const float* wif   = (const float*)d_in[4];
  const float* whf   = (const float*)d_in[5];
  const float* bif   = (const float*)d_in[6];
  const float* bhf   = (const float*)d_in[7];
  const float* wib   = (const float*)d_in[8];
  const float* whb   = (const float*)d_in[9];
  const float* bib   = (const float*)d_in[10];
  const float* bhb   = (const float*)d_in[11];
  const float* wtag  = (const float*)d_in[12];
  const float* btag  = (const float*)d_in[13];
  const float* trans = (const float*)d_in[14];
  const float* st    = (const float*)d_in[15];
  const float* en    = (const float*)d_in[16];

  char* wsb = (char*)d_ws;
  float* em_f = (float*)wsb;                                   //  6,553,600 B
  float* em_b = (float*)(wsb + 6553600);                       //  6,553,600 B

  lstm_fused4x2<<<128, 1024, 0, stream>>>(tok, emb, wif, wib, bif, bhf,
                                          bib, bhb, whf, whb, wtag, btag,
                                          em_f, em_b, (float*)d_out);
  crf_chunks<<<BB * CHN, 128, 0, stream>>>(em_f, em_b, trans);
  crf_combine<<<BB, 128, 0, stream>>>(em_f, em_b, tags, lens, trans, st, en,
                                      (float*)d_out);
}

// Round 12
// 407.478 us; speedup vs baseline: 2.7728x; 2.7728x over previous
//
#include <hip/hip_runtime.h>
#include <cstdint>
#include <cstddef>

#define BB 128
#define TT 512
#define DD 100
#define HH 100
#define NG 400   // 4*H
#define LL 25
#define TS 32    // scan tile (steps per burst)
#define NTILE 16
#define F_LOG2E 1.44269504088896340736f
#define F_LN2   0.69314718055994530942f

typedef __decltype(__builtin_amdgcn_cvt_pkrtz(0.f, 0.f)) h2_t;
typedef _Float16 v8h __attribute__((ext_vector_type(8)));
typedef float v4f __attribute__((ext_vector_type(4)));

__device__ __forceinline__ h2_t bc_h2(unsigned int u) {
  return __builtin_bit_cast(h2_t, u);
}
__device__ __forceinline__ unsigned int pk(float x, float y) {
  return __builtin_bit_cast(unsigned int, __builtin_amdgcn_cvt_pkrtz(x, y));
}
// round-to-nearest-even fp16 pack (matches scalar (__fp16) h-store numerics)
__device__ __forceinline__ unsigned int pk_rte(float x, float y) {
  unsigned short a = __builtin_bit_cast(unsigned short, (__fp16)x);
  unsigned short c = __builtin_bit_cast(unsigned short, (__fp16)y);
  return (unsigned int)a | ((unsigned int)c << 16);
}

__device__ __forceinline__ float fdot2(h2_t a, h2_t b, float c) {
#if __has_builtin(__builtin_amdgcn_fdot2)
  return __builtin_amdgcn_fdot2(a, b, c, false);
#else
  return c + (float)a[0] * (float)b[0] + (float)a[1] * (float)b[1];
#endif
}

__device__ __forceinline__ float fexp2(float x) { return __builtin_amdgcn_exp2f(x); }
__device__ __forceinline__ float flog2(float x) { return __builtin_amdgcn_logf(x); }
__device__ __forceinline__ float frcp(float x)  { return __builtin_amdgcn_rcpf(x); }

__device__ __forceinline__ float sigmoid_f(float x) {
  return frcp(1.f + fexp2(-F_LOG2E * x));
}
__device__ __forceinline__ float tanh_f(float x) {
  float e = fexp2(2.f * F_LOG2E * x);
  return 1.f - 2.f * frcp(e + 1.f);
}

template <int CTRL>
__device__ __forceinline__ float qadd(float v) {
#if __has_builtin(__builtin_amdgcn_mov_dpp)
  int m = __builtin_amdgcn_mov_dpp(__builtin_bit_cast(int, v), CTRL, 0xF, 0xF, true);
  return v + __builtin_bit_cast(float, m);
#else
  int x = (CTRL == 177) ? 1 : 2;
  return v + __shfl_xor(v, x);
#endif
}

template <int LANE>
__device__ __forceinline__ float qbcast(float v) {
#if __has_builtin(__builtin_amdgcn_mov_dpp)
  int m = __builtin_amdgcn_mov_dpp(__builtin_bit_cast(int, v), LANE * 0x55, 0xF, 0xF, true);
  return __builtin_bit_cast(float, m);
#else
  return __shfl(v, (threadIdx.x & 63 & ~3) + LANE);
#endif
}

__device__ __forceinline__ float rfl(float v) {
  return __builtin_bit_cast(float,
      __builtin_amdgcn_readfirstlane(__builtin_bit_cast(int, v)));
}

__device__ __forceinline__ void wave_fence() {
#if __has_builtin(__builtin_amdgcn_wave_barrier)
  __builtin_amdgcn_wave_barrier();
#endif
}

// LDS-visibility-only barrier (vmcnt left free): imm 0xC07F.
__device__ __forceinline__ void lds_barrier() {
  __builtin_amdgcn_s_waitcnt(0xC07F);
  __builtin_amdgcn_s_barrier();
}

// ---------------------------------------------------------------------------
// FUSED BiLSTM + x-GEMM + emissions (v4 structure, (512,1) — round-7 best:
// 280 us kernel / 410.0 us total, restored as final).
// Session conclusion: the 512-step recurrence is latency-chain-bound at
// ~1100-1280 cyc/step (LDS h-roundtrip + 25-deep fdot2 chain + act chain +
// 8-wave barrier). Attacks tried and falsified: fewer/more scan waves
// (v4/v6), MFMA-batched recurrence (scan16: 3270 cyc/step), kernel
// decomposition (scan_lean: no faster, +2 launches), VGPR-cap lift (r7:
// null — compiler chooses 128), cross-dir SMT fill via 1024-thr fuse
// (r8-r10: hipcc caps VGPR at 64 for 1024-thr blocks -> forced spill,
// mechanism untestable). Fixed overhead ~105-125 us + CRF ~25 us on top.
// ---------------------------------------------------------------------------
__global__ __launch_bounds__(512, 1) void lstm_fused4(
    const int* __restrict__ tok, const float* __restrict__ emb,
    const float* __restrict__ w_ih_f, const float* __restrict__ w_ih_b,
    const float* __restrict__ b_ih_f, const float* __restrict__ b_hh_f,
    const float* __restrict__ b_ih_b, const float* __restrict__ b_hh_b,
    const float* __restrict__ w_hh_f, const float* __restrict__ w_hh_b,
    const float* __restrict__ w_tag, const float* __restrict__ b_tag,
    float* __restrict__ em_f, float* __restrict__ em_b,
    float* __restrict__ out_zero)
{
  const int tid = threadIdx.x;
  const int b   = blockIdx.x & 127;
  const int dir = blockIdx.x >> 7;
  if (blockIdx.x == 0 && tid == 0) *out_zero = 0.f;
  const float* w_hh = dir ? w_hh_b : w_hh_f;
  const float* w_ih = dir ? w_ih_b : w_ih_f;
  const float* b_ih = dir ? b_ih_b : b_ih_f;
  const float* b_hh = dir ? b_hh_b : b_hh_f;
  float* emo = dir ? em_b : em_f;

  __shared__ __align__(16) unsigned short gin_lds[TS * 400];   // 25.6 KB
  __shared__ __align__(16) unsigned int xlds[TS * 68];         // 8.7 KB
  __shared__ __align__(16) unsigned int hhist[TS * 68];        // 8.7 KB (h history)
  __shared__ __align__(16) unsigned int hls0[56];
  __shared__ __align__(16) unsigned int hls1[56];

  // burst lane mapping
  const int wv   = tid >> 6;
  const int lane = tid & 63;
  const int l16  = lane & 15;
  const int quad = lane >> 4;
  const int c0b  = (25 * wv) >> 3;
  const int c1b  = (25 * (wv + 1)) >> 3;
  const int ncol = c1b - c0b;   // 3 or 4

  // ---- one-time: B fragments from global w_ih into registers ----
  v8h bfr[4][4];
  int pcol[4];
#pragma unroll
  for (int ci = 0; ci < 4; ++ci) {
    const int cc = (ci < ncol) ? (c0b + ci) : c0b;
    const int n  = 16 * cc + l16;
    const float* wr = w_ih + (size_t)n * DD;
#pragma unroll
    for (int f = 0; f < 3; ++f) {
      const float* wp = wr + f * 32 + quad * 8;
      float4 va = *(const float4*)(wp);
      float4 vb = *(const float4*)(wp + 4);
      uint4 u;
      u.x = pk(va.x, va.y); u.y = pk(va.z, va.w);
      u.z = pk(vb.x, vb.y); u.w = pk(vb.z, vb.w);
      bfr[ci][f] = __builtin_bit_cast(v8h, u);
    }
    {
      uint4 u = {0u, 0u, 0u, 0u};
      if (quad == 0) {
        float4 va = *(const float4*)(wr + 96);
        u.x = pk(va.x, va.y); u.y = pk(va.z, va.w);
      }
      bfr[ci][3] = __builtin_bit_cast(v8h, u);
    }
    const int qn = (n * 41) >> 12;            // n/100 for n<400
    pcol[ci] = ((n - 100 * qn) << 2) + qn;    // store permutation
  }

  // ---- xlds / hhist K-pad zero ----
  for (int i = tid; i < TS * 18; i += 512) {
    int row = i / 18;
    int d = i - row * 18;
    xlds[row * 68 + 50 + d] = 0u;
    hhist[row * 68 + 50 + d] = 0u;
  }

  // ---- scan state: waves 0-3, lane = 2*j + s2 ----
  const bool uact = tid < 200;
  const int j  = tid >> 1;
  const int s2 = tid & 1;

  h2_t wG0[25], wG1[25], wG2[25], wG3[25];
  float bias0 = 0.f, bias1 = 0.f, bias2 = 0.f, bias3 = 0.f;
  if (uact) {
    const float* r0 = w_hh + (size_t)(0 * 100 + j) * HH + 50 * s2;
    const float* r1 = w_hh + (size_t)(1 * 100 + j) * HH + 50 * s2;
    const float* r2 = w_hh + (size_t)(2 * 100 + j) * HH + 50 * s2;
    const float* r3 = w_hh + (size_t)(3 * 100 + j) * HH + 50 * s2;
#pragma unroll
    for (int d = 0; d < 25; ++d) {
      float2 v0 = *(const float2*)(r0 + 2 * d);
      float2 v1 = *(const float2*)(r1 + 2 * d);
      float2 v2 = *(const float2*)(r2 + 2 * d);
      float2 v3 = *(const float2*)(r3 + 2 * d);
      wG0[d] = __builtin_amdgcn_cvt_pkrtz(v0.x, v0.y);
      wG1[d] = __builtin_amdgcn_cvt_pkrtz(v1.x, v1.y);
      wG2[d] = __builtin_amdgcn_cvt_pkrtz(v2.x, v2.y);
      wG3[d] = __builtin_amdgcn_cvt_pkrtz(v3.x, v3.y);
    }
    bias0 = b_ih[j]       + b_hh[j];
    bias1 = b_ih[100 + j] + b_hh[100 + j];
    bias2 = b_ih[200 + j] + b_hh[200 + j];
    bias3 = b_ih[300 + j] + b_hh[300 + j];
  }

  // ---- emission GEMM state: waves 4-7 ----
  const int ew    = wv - 4;
  const int ecb   = ew & 1;          // label col-block (0: l 0-15, 1: l 16-24)
  const int erg   = (ew >> 1) & 1;   // step row-group (0: 0-15, 1: 16-31)
  const int encol = 16 * ecb + l16;  // output label index
  const bool eact2 = (wv >= 4) && (encol < LL);
  v8h etag[4];
  float ebias = 0.f;
  if (wv >= 4) {
#pragma unroll
    for (int f = 0; f < 3; ++f) {
      uint4 u = {0u, 0u, 0u, 0u};
      if (eact2) {
        const float* wp = w_tag + (size_t)encol * 200 + dir * 100 + f * 32 + quad * 8;
        float4 va = *(const float4*)(wp);
        float4 vb = *(const float4*)(wp + 4);
        u.x = pk(va.x, va.y); u.y = pk(va.z, va.w);
        u.z = pk(vb.x, vb.y); u.w = pk(vb.z, vb.w);
      }
      etag[f] = __builtin_bit_cast(v8h, u);
    }
    {
      uint4 u = {0u, 0u, 0u, 0u};
      if (eact2 && quad == 0) {
        float4 va = *(const float4*)(w_tag + (size_t)encol * 200 + dir * 100 + 96);
        u.x = pk(va.x, va.y); u.y = pk(va.z, va.w);
      }
      etag[3] = __builtin_bit_cast(v8h, u);
    }
    if (eact2 && dir == 0) ebias = b_tag[encol];
  }

  if (tid < 56) { hls0[tid] = 0u; hls1[tid] = 0u; }

  // x staging mapping: thread t<416 covers (row = t/13, seg = t%13)
  const int tprow = tid / 13;
  const int tps   = tid - 13 * tprow;
  const bool tp_act = tid < 416;

  // initial x prefetch (tile 0)
  float4 xa = {0, 0, 0, 0}, xb = {0, 0, 0, 0};
  if (tp_act) {
    int ii = tprow;
    int tt = dir ? (TT - 1 - ii) : ii;
    int tk = tok[b * TT + tt];
    const float* xp = emb + (size_t)tk * DD + 8 * tps;
    xa = *(const float4*)xp;
    if (tps < 12) xb = *(const float4*)(xp + 4);
  }

  float c = 0.f;
  uint2 gnext = {0u, 0u};

#define SD2(d, hw) { h2_t hv = bc_h2(hw);                                  \
  p0 = fdot2(wG0[d], hv, p0); p1 = fdot2(wG1[d], hv, p1);                  \
  p2 = fdot2(wG2[d], hv, p2); p3 = fdot2(wG3[d], hv, p3); }

#define SCAN2(HRD, HWR, ROW)                                               \
  {                                                                        \
    if (uact) {                                                            \
      uint2 gcurr = gnext;                                                 \
      int nr = ((ROW) < TS - 1) ? (ROW) + 1 : TS - 1;                      \
      gnext = ((const uint2*)(gin_lds + nr * 400))[j];                     \
      const unsigned int* hp = (HRD) + 28 * s2;                            \
      uint4 u0 = *((const uint4*)hp);                                      \
      uint4 u1 = *((const uint4*)(hp + 4));                                \
      uint4 u2 = *((const uint4*)(hp + 8));                                \
      uint4 u3 = *((const uint4*)(hp + 12));                               \
      uint4 u4 = *((const uint4*)(hp + 16));                               \
      uint4 u5 = *((const uint4*)(hp + 20));                               \
      unsigned int u6 = hp[24];                                            \
      float p0 = 0.f, p1 = 0.f, p2 = 0.f, p3 = 0.f;                        \
      SD2(0, u0.x)  SD2(1, u0.y)  SD2(2, u0.z)  SD2(3, u0.w)               \
      SD2(4, u1.x)  SD2(5, u1.y)  SD2(6, u1.z)  SD2(7, u1.w)               \
      SD2(8, u2.x)  SD2(9, u2.y)  SD2(10, u2.z) SD2(11, u2.w)              \
      SD2(12, u3.x) SD2(13, u3.y) SD2(14, u3.z) SD2(15, u3.w)              \
      SD2(16, u4.x) SD2(17, u4.y) SD2(18, u4.z) SD2(19, u4.w)              \
      SD2(20, u5.x) SD2(21, u5.y) SD2(22, u5.z) SD2(23, u5.w)              \
      SD2(24, u6)                                                          \
      p0 = qadd<177>(p0); p1 = qadd<177>(p1);                              \
      p2 = qadd<177>(p2); p3 = qadd<177>(p3);                              \
      h2_t glo = bc_h2(gcurr.x), ghi = bc_h2(gcurr.y);                     \
      float gi = p0 + bias0 + (float)glo[0];                               \
      float gf = p1 + bias1 + (float)glo[1];                               \
      float gg = p2 + bias2 + (float)ghi[0];                               \
      float go = p3 + bias3 + (float)ghi[1];                               \
      float iv = sigmoid_f(gi);                                            \
      float fv = sigmoid_f(gf);                                            \
      float gv = tanh_f(gg);                                               \
      float ov = sigmoid_f(go);                                            \
      c = fmaf(fv, c, iv * gv);                                            \
      float hvv = ov * tanh_f(c);                                          \
      float hnb = qbcast<2>(hvv);                                          \
      if ((tid & 3) == 0) {                                                \
        int k = tid >> 2;                                                  \
        unsigned int val = pk_rte(hvv, hnb);                               \
        (HWR)[k + (k >= 25 ? 3 : 0)] = val;                                \
        hhist[(ROW) * 68 + k] = val;                                       \
      }                                                                    \
    }                                                                      \
    lds_barrier();                                                         \
  }

#define EMIT_GEMM(TB)                                                      \
  {                                                                        \
    const unsigned int* hb = hhist + (erg * 16 + l16) * 68 + quad * 4;     \
    v8h ah0 = __builtin_bit_cast(v8h, *(const uint4*)(hb));                \
    v8h ah1 = __builtin_bit_cast(v8h, *(const uint4*)(hb + 16));           \
    v8h ah2 = __builtin_bit_cast(v8h, *(const uint4*)(hb + 32));           \
    v8h ah3 = __builtin_bit_cast(v8h, *(const uint4*)(hb + 48));           \
    v4f ea = {0.f, 0.f, 0.f, 0.f};                                         \
    ea = __builtin_amdgcn_mfma_f32_16x16x32_f16(ah0, etag[0], ea, 0, 0, 0);\
    ea = __builtin_amdgcn_mfma_f32_16x16x32_f16(ah1, etag[1], ea, 0, 0, 0);\
    ea = __builtin_amdgcn_mfma_f32_16x16x32_f16(ah2, etag[2], ea, 0, 0, 0);\
    ea = __builtin_amdgcn_mfma_f32_16x16x32_f16(ah3, etag[3], ea, 0, 0, 0);\
    if (eact2) {                                                           \
      const int tb = (TB) + erg * 16 + quad * 4;                           \
      _Pragma("unroll")                                                    \
      for (int r = 0; r < 4; ++r) {                                        \
        int t = dir ? (TT - 1 - (tb + r)) : (tb + r);                      \
        emo[((size_t)b * TT + t) * LL + encol] = ea[r] + ebias;            \
      }                                                                    \
    }                                                                      \
  }

  __syncthreads();  // pads / hls init complete

  for (int T = 0; T < NTILE; ++T) {
    // ---- write prefetched x regs to xlds ----
    if (tp_act) {
      unsigned int* xr = xlds + tprow * 68 + 4 * tps;
      if (tps < 12) {
        uint4 u;
        u.x = pk(xa.x, xa.y); u.y = pk(xa.z, xa.w);
        u.z = pk(xb.x, xb.y); u.w = pk(xb.z, xb.w);
        *(uint4*)xr = u;
      } else {
        xr[0] = pk(xa.x, xa.y);
        xr[1] = pk(xa.z, xa.w);
      }
    }
    __syncthreads();

    // ---- BURST ----
    {
      v8h af[2][4];
#pragma unroll
      for (int rg = 0; rg < 2; ++rg)
#pragma unroll
        for (int f = 0; f < 4; ++f)
          af[rg][f] = __builtin_bit_cast(v8h,
              *(const uint4*)(xlds + (rg * 16 + l16) * 68 + f * 16 + quad * 4));

      // kick off next tile's x prefetch (stays in flight through the scan)
      if (tp_act && T + 1 < NTILE) {
        int ii = (T + 1) * TS + tprow;
        int tt = dir ? (TT - 1 - ii) : ii;
        int tk = tok[b * TT + tt];
        const float* xp = emb + (size_t)tk * DD + 8 * tps;
        xa = *(const float4*)xp;
        if (tps < 12) xb = *(const float4*)(xp + 4);
      }

      __fp16* gout = (__fp16*)gin_lds;
#pragma unroll
      for (int ci = 0; ci < 4; ++ci) {
        if (ci >= ncol) break;
        const int p = pcol[ci];
#pragma unroll
        for (int rg = 0; rg < 2; ++rg) {
          v4f acc = {0.f, 0.f, 0.f, 0.f};
          acc = __builtin_amdgcn_mfma_f32_16x16x32_f16(af[rg][0], bfr[ci][0], acc, 0, 0, 0);
          acc = __builtin_amdgcn_mfma_f32_16x16x32_f16(af[rg][1], bfr[ci][1], acc, 0, 0, 0);
          acc = __builtin_amdgcn_mfma_f32_16x16x32_f16(af[rg][2], bfr[ci][2], acc, 0, 0, 0);
          acc = __builtin_amdgcn_mfma_f32_16x16x32_f16(af[rg][3], bfr[ci][3], acc, 0, 0, 0);
          const int rowb = rg * 16 + quad * 4;
#pragma unroll
          for (int r = 0; r < 4; ++r)
            gout[(rowb + r) * 400 + p] = (__fp16)acc[r];
        }
      }

      // ---- emission GEMM for previous tile's h (waves 4-7) ----
      if (wv >= 4 && T > 0) {
        EMIT_GEMM((T - 1) * TS)
      }
    }
    __syncthreads();
    if (uact) gnext = ((const uint2*)gin_lds)[j];

    // ---- TS scan steps ----
    for (int it = 0; it < TS; it += 2) {
      SCAN2(hls0, hls1, it)
      SCAN2(hls1, hls0, it + 1)
    }
  }

  // epilogue: emissions for the final tile (hhist holds tile NTILE-1's h;
  // last scan step ended with lds_barrier, so it is visible)
  if (wv >= 4) {
    EMIT_GEMM((NTILE - 1) * TS)
  }
#undef EMIT_GEMM
#undef SCAN2
#undef SD2
}

// ===========================================================================
// CRF — parallel chunked scan (round-1 versions, verified).
// ===========================================================================
#define CHN  8
#define CLEN 64
__device__ __align__(16) float g_PT[(size_t)BB * CHN * LL * 28];  // 2.87 MB

__global__ __launch_bounds__(128, 2) void crf_chunks(
    const float* __restrict__ em_f, const float* __restrict__ em_b,
    const float* __restrict__ trans)
{
  const int tid = threadIdx.x;
  const int b   = blockIdx.x >> 3;
  const int c   = blockIdx.x & 7;
  const int ts  = c * CLEN;

  __shared__ __align__(16) float Al[2][LL][28];   // double-buffered A
  __shared__ __align__(16) float el[CLEN][32];    // e_t[j] = exp(em_t[j])

  // ---- stage e rows (2 threads per time step) ----
  {
    const int row  = tid >> 1;        // 0..63
    const int half = tid & 1;
    const int jb   = half ? 13 : 0;
    const int nj   = half ? 12 : 13;
    const float* pf = em_f + ((size_t)b * TT + ts + row) * LL;
    const float* pb = em_b + ((size_t)b * TT + ts + row) * LL;
    for (int q = 0; q < nj; ++q) {
      int jj = jb + q;
      el[row][jj] = fexp2((pf[jj] + pb[jj]) * F_LOG2E);
    }
  }

  const bool lact = tid < 125;
  const int i  = tid / 5;          // output row 0..24
  const int jg = tid - 5 * i;      // col group 0..4
  const int j0 = 5 * jg;

  // ---- E' = exp(T)*2^-5, columns j0..j0+4, in registers (125 VGPR) ----
  float E[25][5];
  if (lact) {
#pragma unroll
    for (int k = 0; k < 25; ++k) {
      const float* tr = trans + k * 25 + j0;
#pragma unroll
      for (int u = 0; u < 5; ++u)
        E[k][u] = fexp2(tr[u] * F_LOG2E - 5.f);
    }
    // A = I
#pragma unroll
    for (int u = 0; u < 5; ++u)
      Al[0][i][j0 + u] = (i == j0 + u) ? 1.f : 0.f;
  }
  __syncthreads();

  int p = 0;
  const int s0 = (c == 0) ? 1 : 0;   // chunk 0 covers t = 1..63
  for (int st = s0; st < CLEN; ++st) {
    if (lact) {
      const float* ar = &Al[p][i][0];
      float4 q0 = *(const float4*)(ar);
      float4 q1 = *(const float4*)(ar + 4);
      float4 q2 = *(const float4*)(ar + 8);
      float4 q3 = *(const float4*)(ar + 12);
      float4 q4 = *(const float4*)(ar + 16);
      float4 q5 = *(const float4*)(ar + 20);
      float a24 = ar[24];
      float e0 = el[st][j0];
      float e1 = el[st][j0 + 1];
      float e2 = el[st][j0 + 2];
      float e3 = el[st][j0 + 3];
      float e4 = el[st][j0 + 4];
      float av[25] = {q0.x, q0.y, q0.z, q0.w, q1.x, q1.y, q1.z, q1.w,
                      q2.x, q2.y, q2.z, q2.w, q3.x, q3.y, q3.z, q3.w,
                      q4.x, q4.y, q4.z, q4.w, q5.x, q5.y, q5.z, q5.w, a24};
      float c0 = 0.f, c1 = 0.f, c2 = 0.f, c3 = 0.f, c4 = 0.f;
#pragma unroll
      for (int k = 0; k < 25; ++k) {
        float avk = av[k];
        c0 = fmaf(avk, E[k][0], c0);
        c1 = fmaf(avk, E[k][1], c1);
        c2 = fmaf(avk, E[k][2], c2);
        c3 = fmaf(avk, E[k][3], c3);
        c4 = fmaf(avk, E[k][4], c4);
      }
      float* wr = &Al[p ^ 1][i][j0];
      wr[0] = c0 * e0; wr[1] = c1 * e1; wr[2] = c2 * e2;
      wr[3] = c3 * e3; wr[4] = c4 * e4;
    }
    __syncthreads();
    p ^= 1;
  }

  // ---- store P transposed: g_PT[(b*8+c)*25 + j][i], row stride 28 ----
  if (lact) {
    const size_t base = ((size_t)(b * CHN + c)) * LL;
#pragma unroll
    for (int u = 0; u < 5; ++u)
      g_PT[(base + (j0 + u)) * 28 + i] = Al[p][i][j0 + u];
  }
}

__global__ __launch_bounds__(128) void crf_combine(
    const float* __restrict__ em_f, const float* __restrict__ em_b,
    const int* __restrict__ tags, const int* __restrict__ lengths,
    const float* __restrict__ trans,
    const float* __restrict__ startt, const float* __restrict__ endt,
    float* __restrict__ out)
{
  const int tid = threadIdx.x;
  const int b   = blockIdx.x;

  __shared__ __align__(16) float Vs[28];

  if (tid < 64) {
    // -------- wave 0: logZ via chunk-matrix chain --------
    const int lane = tid;
    const int j = (lane < LL) ? lane : 0;
    const float* ef0 = em_f + (size_t)b * TT * LL;
    const float* eb0 = em_b + (size_t)b * TT * LL;
    float v = fexp2((startt[j] + ef0[j] + eb0[j]) * F_LOG2E);  // alpha0
    float C = 0.f;  // accumulated log2 scale
    for (int c = 0; c < CHN; ++c) {
      if (lane < LL) Vs[lane] = v;
      wave_fence();
      float4 s0 = *(const float4*)(Vs);
      float4 s1 = *(const float4*)(Vs + 4);
      float4 s2 = *(const float4*)(Vs + 8);
      float4 s3 = *(const float4*)(Vs + 12);
      float4 s4 = *(const float4*)(Vs + 16);
      float4 s5 = *(const float4*)(Vs + 20);
      float s24 = Vs[24];
      wave_fence();
      const float* pr = g_PT + ((size_t)(b * CHN + c) * LL + j) * 28;
      float4 p0 = *(const float4*)(pr);
      float4 p1 = *(const float4*)(pr + 4);
      float4 p2 = *(const float4*)(pr + 8);
      float4 p3 = *(const float4*)(pr + 12);
      float4 p4 = *(const float4*)(pr + 16);
      float4 p5 = *(const float4*)(pr + 20);
      float p24 = pr[24];
      float nv = s0.x * p0.x;
      nv = fmaf(s0.y, p0.y, nv); nv = fmaf(s0.z, p0.z, nv); nv = fmaf(s0.w, p0.w, nv);
      nv = fmaf(s1.x, p1.x, nv); nv = fmaf(s1.y, p1.y, nv);
      nv = fmaf(s1.z, p1.z, nv); nv = fmaf(s1.w, p1.w, nv);
      nv = fmaf(s2.x, p2.x, nv); nv = fmaf(s2.y, p2.y, nv);
      nv = fmaf(s2.z, p2.z, nv); nv = fmaf(s2.w, p2.w, nv);
      nv = fmaf(s3.x, p3.x, nv); nv = fmaf(s3.y, p3.y, nv);
      nv = fmaf(s3.z, p3.z, nv); nv = fmaf(s3.w, p3.w, nv);
      nv = fmaf(s4.x, p4.x, nv); nv = fmaf(s4.y, p4.y, nv);
      nv = fmaf(s4.z, p4.z, nv); nv = fmaf(s4.w, p4.w, nv);
      nv = fmaf(s5.x, p5.x, nv); nv = fmaf(s5.y, p5.y, nv);
      nv = fmaf(s5.z, p5.z, nv); nv = fmaf(s5.w, p5.w, nv);
      nv = fmaf(s24, p24, nv);
      // renormalize by lane-0 exponent (all entries same magnitude class)
      float nv0 = rfl(nv);
      int k = ((__builtin_bit_cast(int, nv0) >> 23) & 255) - 127;
      k = (k > 100) ? 100 : ((k < -100) ? -100 : k);
      float scl = __builtin_bit_cast(float, (127 - k) << 23);
      v = nv * scl;
      C += (float)k;
    }
    float term = (lane < LL) ? v * fexp2(endt[j] * F_LOG2E) : 0.f;
    for (int o = 32; o > 0; o >>= 1) term += __shfl_down(term, o);
    if (lane == 0)
      atomicAdd(out, (flog2(term) + C + 5.f * 511.f) * F_LN2);
  } else {
    // -------- wave 1: gold path score --------
    const int lane = tid & 63;
    const int len = lengths[b];
    float acc = 0.f;
#pragma unroll
    for (int k = 0; k < 8; ++k) {
      int t = k * 64 + lane;
      int tg = tags[b * TT + t];
      size_t ei = ((size_t)b * TT + t) * LL + tg;
      float e = em_f[ei] + em_b[ei];
      float term;
      if (t == 0) term = startt[tg] + e;
      else        term = trans[tags[b * TT + t - 1] * LL + tg] + e;
      if (t == len - 1) term += endt[tg];
      if (t < len) acc += term;
    }
    for (int o = 32; o > 0; o >>= 1) acc += __shfl_down(acc, o);
    if (lane == 0) atomicAdd(out, -acc);
  }
}

extern "C" void kernel_launch(void* const* d_in, const int* in_sizes, int n_in,
                              void* d_out, int out_size, void* d_ws, size_t ws_size,
                              hipStream_t stream) {
  const int*   tok   = (const int*)d_in[0];
  const int*   tags  = (const int*)d_in[1];
  const int*   lens  = (const int*)d_in[2];
  const float* emb   = (const float*)d_in[3];
  const float* wif   = (const float*)d_in[4];
  const float* whf   = (const float*)d_in[5];
  const float* bif   = (const float*)d_in[6];
  const float* bhf   = (const float*)d_in[7];
  const float* wib   = (const float*)d_in[8];
  const float* whb   = (const float*)d_in[9];
  const float* bib   = (const float*)d_in[10];
  const float* bhb   = (const float*)d_in[11];
  const float* wtag  = (const float*)d_in[12];
  const float* btag  = (const float*)d_in[13];
  const float* trans = (const float*)d_in[14];
  const float* st    = (const float*)d_in[15];
  const float* en    = (const float*)d_in[16];

  char* wsb = (char*)d_ws;
  float* em_f = (float*)wsb;                                   //  6,553,600 B
  float* em_b = (float*)(wsb + 6553600);                       //  6,553,600 B

  lstm_fused4<<<256, 512, 0, stream>>>(tok, emb, wif, wib, bif, bhf, bib, bhb,
                                       whf, whb, wtag, btag, em_f, em_b,
                                       (float*)d_out);
  crf_chunks<<<BB * CHN, 128, 0, stream>>>(em_f, em_b, trans);
  crf_combine<<<BB, 128, 0, stream>>>(em_f, em_b, tags, lens, trans, st, en,
                                      (float*)d_out);
}